// Round 13
// baseline (396.564 us; speedup 1.0000x reference)
//
#include <hip/hip_runtime.h>
#include <math.h>

// ---------------------------------------------------------------------------
// Z_exp = Tr(M rho^x4) = degree-4 poly in Bloch (x,y,z), 35 monomials.
// R12 lesson: chain cost = per-lane instruction count x exposed latency
// (~20cyc/instr at 1 wave/SIMD); NOT barrier-bound. R10 structure wasted
// time running chain+eval SERIALLY in every block (23.7us = 18 + 5).
// R13: producer/consumer. Block 0 = R10's verbatim 4-wave chain -> coef in
// d_ws -> threadfence -> release flag. Blocks 1..N = eval: prep FIRST
// (overlaps chain), spin on flag (acquire, s_sleep backoff), 35 FMAs, store.
// All 1025 blocks resident (5 blocks/CU by LDS) -> no starvation.
// ---------------------------------------------------------------------------

struct cpx { float re, im; };

__device__ __forceinline__ cpx cmul(cpx a, cpx b) {
    return { a.re * b.re - a.im * b.im, a.re * b.im + a.im * b.re };
}

// ---- compile-time Pauli-string -> monomial grouping (data-independent) ----
struct MonoTab { unsigned char cnt[125]; unsigned char idx[125][24]; };

constexpr int mono_of(int p) {
    int a = 0, b = 0, c = 0;
    for (int k = 0; k < 4; ++k) {
        const int pk = (p >> (2 * k)) & 3;   // 0=I,1=X,2=Y,3=Z
        a += (pk == 1); b += (pk == 2); c += (pk == 3);
    }
    return (a * 5 + b) * 5 + c;
}
constexpr MonoTab build_tab() {
    MonoTab t{};
    for (int m = 0; m < 125; ++m) {
        t.cnt[m] = 0;
        for (int k = 0; k < 24; ++k) t.idx[m][k] = 0;
    }
    for (int p = 0; p < 256; ++p) {          // ascending p: fixed sum order
        const int m = mono_of(p);
        t.idx[m][t.cnt[m]++] = (unsigned char)p;
    }
    return t;
}
__constant__ const MonoTab TAB = build_tab();

#define COEF_MAGIC 0x13579BDF

__global__ __launch_bounds__(256) void fused_kernel(
    const float4* __restrict__ in4, const float* __restrict__ w_U,
    const float* __restrict__ w_RXZX, const float* __restrict__ scale_p,
    const float* __restrict__ bias_p, float2* __restrict__ out2,
    float* __restrict__ coef, int* __restrict__ flag, int B2)
{
    __shared__ cpx   R[24][2][2];
    __shared__ float ISc[6], ISs[6];
    __shared__ cpx   L[6][16][16];
    __shared__ cpx   P1[3][16][16];
    __shared__ cpx   Dm[16][16];
    __shared__ cpx   Wf[16][16];
    __shared__ cpx   Mm[16][16];
    __shared__ float cp[256];

    const int tid = threadIdx.x;
    const int bid = blockIdx.x;

    if (bid != 0) {
        // ================= EVAL BLOCK ======================================
        const int eidx = (bid - 1) * 256 + tid;      // float4 index (2 elems)
        float4 f = make_float4(0.f, 0.f, 0.f, 0.f);
        if (eidx < B2) f = in4[eidx];
        const float scale = scale_p[0], bias = bias_p[0];

        // coef-independent prep (overlaps the producer's chain)
        float xp[2][5], yp[2][5], zp[2][5];
        #pragma unroll
        for (int e = 0; e < 2; ++e) {
            const float f0 = e ? f.z : f.x;
            const float f1 = e ? f.w : f.y;
            float s0, c0, s1, c1;
            sincosf(f0, &s0, &c0);
            sincosf(f1, &s1, &c1);
            const float x = s1 * c0, y = s1 * s0, z = c1;
            xp[e][0] = yp[e][0] = zp[e][0] = 1.f;
            #pragma unroll
            for (int k = 1; k < 5; ++k) {
                xp[e][k] = xp[e][k - 1] * x;
                yp[e][k] = yp[e][k - 1] * y;
                zp[e][k] = zp[e][k - 1] * z;
            }
        }

        // spin until producer publishes coefficients (agent-scope acquire)
        while (__hip_atomic_load(flag, __ATOMIC_ACQUIRE,
                                 __HIP_MEMORY_SCOPE_AGENT) != COEF_MAGIC) {
            __builtin_amdgcn_s_sleep(8);
        }

        if (eidx >= B2) return;

        float2 res;
        #pragma unroll
        for (int e = 0; e < 2; ++e) {
            float Z = 0.f;
            #pragma unroll
            for (int a = 0; a <= 4; ++a)
                #pragma unroll
                for (int b = 0; b <= 4 - a; ++b)
                    #pragma unroll
                    for (int c = 0; c <= 4 - a - b; ++c)
                        Z = fmaf(coef[(a * 5 + b) * 5 + c],
                                 xp[e][a] * yp[e][b] * zp[e][c], Z);
            const float noise = 0.04472135954999579f * (Z * Z - 1.f) * 0.25f;
            const float v = scale * (Z + noise) + bias;
            if (e) res.y = v; else res.x = v;
        }
        out2[eidx] = res;
        return;
    }

    // ================= PRODUCER BLOCK (bid==0): verbatim R10 chain =========
    const int i = tid >> 4, j = tid & 15;

    // ---- Phase 1: 2x2 RXZX gates + iSWAP params ----
    if (tid < 24) {
        const float ta = w_RXZX[tid * 3 + 0];
        const float tb = w_RXZX[tid * 3 + 1];
        const float tc = w_RXZX[tid * 3 + 2];
        float sa, ca, sb, cb, sc, cc;
        sincosf(0.5f * ta, &sa, &ca);
        sincosf(0.5f * tb, &sb, &cb);
        sincosf(0.5f * tc, &sc, &cc);
        // RX(t)=[[c,-is],[-is,c]], RZ(t)=diag(c-is,c+is); g = RX(a)RZ(b)RX(c)
        const cpx e0 = { cb, -sb };
        const cpx e1 = { cb,  sb };
        const cpx T00 = { e0.re * cc, e0.im * cc };
        const cpx T01 = { -e0.im * (-sc), e0.re * (-sc) };
        const cpx T10 = { -e1.im * (-sc), e1.re * (-sc) };
        const cpx T11 = { e1.re * cc, e1.im * cc };
        R[tid][0][0] = { ca * T00.re + sa * T10.im, ca * T00.im - sa * T10.re };
        R[tid][0][1] = { ca * T01.re + sa * T11.im, ca * T01.im - sa * T11.re };
        R[tid][1][0] = { sa * T00.im + ca * T10.re, -sa * T00.re + ca * T10.im };
        R[tid][1][1] = { sa * T01.im + ca * T11.re, -sa * T01.re + ca * T11.im };
    } else if (tid < 30) {
        const int l = tid - 24;
        float s, c;
        sincosf(w_U[l], &s, &c);
        ISc[l] = c;
        ISs[l] = s;
    }
    __syncthreads();

    // ---- Phase 2: L[l] = (GA on iSWAP pair) x (GB on complement pair) ----
    for (int l = 0; l < 6; ++l) {
        const int code = (int)((0xD89C8DC98DC9ULL >> (8 * l)) & 0xFF);
        const int qa = code & 3, qb = (code >> 2) & 3;
        const int qr = (code >> 4) & 3, qs = (code >> 6) & 3;
        const int uAi = (((i >> (3 - qa)) & 1) << 1) | ((i >> (3 - qb)) & 1);
        const int uAj = (((j >> (3 - qa)) & 1) << 1) | ((j >> (3 - qb)) & 1);
        const int uBi = (((i >> (3 - qr)) & 1) << 1) | ((i >> (3 - qs)) & 1);
        const int uBj = (((j >> (3 - qr)) & 1) << 1) | ((j >> (3 - qs)) & 1);
        const int ra = l * 4 + qa, rb = l * 4 + qb;
        cpx ga;
        if (uAj == 0)      ga = cmul(R[ra][uAi >> 1][0], R[rb][uAi & 1][0]);
        else if (uAj == 3) ga = cmul(R[ra][uAi >> 1][1], R[rb][uAi & 1][1]);
        else {
            const cpx k1 = cmul(R[ra][uAi >> 1][0], R[rb][uAi & 1][1]);
            const cpx k2 = cmul(R[ra][uAi >> 1][1], R[rb][uAi & 1][0]);
            const cpx tc = (uAj == 1) ? k1 : k2;   // * cos
            const cpx ts = (uAj == 1) ? k2 : k1;   // * i sin
            const float c = ISc[l], s = ISs[l];
            ga.re = c * tc.re - s * ts.im;
            ga.im = c * tc.im + s * ts.re;
        }
        const cpx gb = cmul(R[l * 4 + qr][uBi >> 1][uBj >> 1],
                            R[l * 4 + qs][uBi & 1][uBj & 1]);
        L[l][i][j] = cmul(ga, gb);
    }
    __syncthreads();

    // ---- Phase 3: P1[m]=L[2m+1]*L[2m], 3 matmuls interleaved ----
    {
        cpx a0 = {0.f, 0.f}, a1 = {0.f, 0.f}, a2 = {0.f, 0.f};
        #pragma unroll 4
        for (int k = 0; k < 16; ++k) {
            const cpx u1 = L[1][i][k], v0 = L[0][k][j];
            const cpx u3 = L[3][i][k], v2 = L[2][k][j];
            const cpx u5 = L[5][i][k], v4 = L[4][k][j];
            a0.re += u1.re * v0.re - u1.im * v0.im;
            a0.im += u1.re * v0.im + u1.im * v0.re;
            a1.re += u3.re * v2.re - u3.im * v2.im;
            a1.im += u3.re * v2.im + u3.im * v2.re;
            a2.re += u5.re * v4.re - u5.im * v4.im;
            a2.im += u5.re * v4.im + u5.im * v4.re;
        }
        P1[0][i][j] = a0; P1[1][i][j] = a1; P1[2][i][j] = a2;
    }
    __syncthreads();

    // ---- Phase 4: D = P1[1]*P1[0], 2-acc k-split ----
    {
        cpx s0 = {0.f, 0.f}, s1 = {0.f, 0.f};
        #pragma unroll 4
        for (int k = 0; k < 8; ++k) {
            const cpx a = P1[1][i][k],     b = P1[0][k][j];
            const cpx c = P1[1][i][k + 8], d = P1[0][k + 8][j];
            s0.re += a.re * b.re - a.im * b.im;
            s0.im += a.re * b.im + a.im * b.re;
            s1.re += c.re * d.re - c.im * d.im;
            s1.im += c.re * d.im + c.im * d.re;
        }
        Dm[i][j] = { s0.re + s1.re, s0.im + s1.im };
    }
    __syncthreads();

    // ---- Phase 5: W = P1[2]*D ----
    {
        cpx s0 = {0.f, 0.f}, s1 = {0.f, 0.f};
        #pragma unroll 4
        for (int k = 0; k < 8; ++k) {
            const cpx a = P1[2][i][k],     b = Dm[k][j];
            const cpx c = P1[2][i][k + 8], d = Dm[k + 8][j];
            s0.re += a.re * b.re - a.im * b.im;
            s0.im += a.re * b.im + a.im * b.re;
            s1.re += c.re * d.re - c.im * d.im;
            s1.im += c.re * d.im + c.im * d.re;
        }
        Wf[i][j] = { s0.re + s1.re, s0.im + s1.im };
    }
    __syncthreads();

    // ---- Phase 6: M[i][j] = sum_k zk conj(W[k][i]) W[k][j] ----
    {
        cpx s0 = {0.f, 0.f}, s1 = {0.f, 0.f};
        #pragma unroll 4
        for (int k = 0; k < 8; ++k) {
            const cpx a = Wf[k][i],     b = Wf[k][j];       // zk=+1
            const cpx c = Wf[k + 8][i], d = Wf[k + 8][j];   // zk=-1
            s0.re += a.re * b.re + a.im * b.im;
            s0.im += a.re * b.im - a.im * b.re;
            s1.re += c.re * d.re + c.im * d.im;
            s1.im += c.re * d.im - c.im * d.re;
        }
        Mm[i][j] = { s0.re - s1.re, s0.im - s1.im };
    }
    __syncthreads();

    // ---- Phase 7: Pauli traces cp[p] = Tr(M*P_p)/16, p = tid ----
    {
        const int p = tid;
        float accre = 0.f;
        #pragma unroll 4
        for (int col = 0; col < 16; ++col) {
            int row = 0;
            cpx val = {1.f, 0.f};
            #pragma unroll
            for (int k = 0; k < 4; ++k) {
                const int pk = (p >> (6 - 2 * k)) & 3;
                const int b = (col >> (3 - k)) & 1;
                int rb = b;
                if (pk == 1) {
                    rb = b ^ 1;
                } else if (pk == 2) {
                    rb = b ^ 1;
                    const cpx fc = {0.f, b ? -1.f : 1.f};
                    val = cmul(val, fc);
                } else if (pk == 3) {
                    if (b) { val.re = -val.re; val.im = -val.im; }
                }
                row |= rb << (3 - k);
            }
            const cpx mv = Mm[col][row];
            accre += mv.re * val.re - mv.im * val.im;
        }
        cp[p] = accre * (1.f / 16.f);
    }
    __syncthreads();

    // ---- Phase 8: collapse + publish ----
    if (tid < 125) {
        const int cnt = TAB.cnt[tid];
        float s = 0.f;
        for (int k = 0; k < cnt; ++k)          // ascending: deterministic
            s += cp[TAB.idx[tid][k]];
        coef[tid] = s;
    }
    __threadfence();                            // push coef to device scope
    __syncthreads();
    if (tid == 0)
        __hip_atomic_store(flag, COEF_MAGIC, __ATOMIC_RELEASE,
                           __HIP_MEMORY_SCOPE_AGENT);
}

extern "C" void kernel_launch(void* const* d_in, const int* in_sizes, int n_in,
                              void* d_out, int out_size, void* d_ws, size_t ws_size,
                              hipStream_t stream) {
    const float* inputs  = (const float*)d_in[0];   // [B,2] f32
    const float* w_U     = (const float*)d_in[1];   // [6]
    const float* w_RXZX  = (const float*)d_in[2];   // [6,4,3]
    const float* scale_p = (const float*)d_in[3];   // [1]
    const float* bias_p  = (const float*)d_in[4];   // [1]
    float* out  = (float*)d_out;
    float* coef = (float*)d_ws;                     // [0..124] coefficients
    int*   flag = (int*)((char*)d_ws + 512);        // publish flag

    const int B  = in_sizes[0] / 2;                 // elements
    const int B2 = B / 2;                           // float4 units (2 el/thr)
    const int eval_blocks = (B2 + 255) / 256;

    fused_kernel<<<1 + eval_blocks, 256, 0, stream>>>(
        (const float4*)inputs, w_U, w_RXZX, scale_p, bias_p,
        (float2*)out, coef, flag, B2);
}

// Round 14
// 16.555 us; speedup vs baseline: 23.9537x; 23.9537x over previous
//
#include <hip/hip_runtime.h>
#include <math.h>

// ---------------------------------------------------------------------------
// Z_exp = Tr(M rho^x4) = degree-4 poly in Bloch (x,y,z), 35 monomials.
// R12: chain cost = per-lane instrs x exposed latency; hiding ~ active
// waves/SIMD. R13: grid-wide flag polling = disaster (serialized agent
// atomics). R14: R10 structure, but chain phases k-SPLIT 4 ways across a
// 1024-thread block (16 waves, 4/SIMD): per-lane work /4, TLP x4.
// Partial-sum phases + short reduces; fixed summation order throughout.
// ---------------------------------------------------------------------------

struct cpx { float re, im; };

__device__ __forceinline__ cpx cmul(cpx a, cpx b) {
    return { a.re * b.re - a.im * b.im, a.re * b.im + a.im * b.re };
}
__device__ __forceinline__ cpx cfma_(cpx acc, cpx a, cpx b) {
    acc.re += a.re * b.re - a.im * b.im;
    acc.im += a.re * b.im + a.im * b.re;
    return acc;
}

// ---- compile-time Pauli-string -> monomial grouping (data-independent) ----
struct MonoTab { unsigned char cnt[125]; unsigned char idx[125][24]; };

constexpr int mono_of(int p) {
    int a = 0, b = 0, c = 0;
    for (int k = 0; k < 4; ++k) {
        const int pk = (p >> (2 * k)) & 3;   // 0=I,1=X,2=Y,3=Z
        a += (pk == 1); b += (pk == 2); c += (pk == 3);
    }
    return (a * 5 + b) * 5 + c;
}
constexpr MonoTab build_tab() {
    MonoTab t{};
    for (int m = 0; m < 125; ++m) {
        t.cnt[m] = 0;
        for (int k = 0; k < 24; ++k) t.idx[m][k] = 0;
    }
    for (int p = 0; p < 256; ++p) {          // ascending p: fixed sum order
        const int m = mono_of(p);
        t.idx[m][t.cnt[m]++] = (unsigned char)p;
    }
    return t;
}
__constant__ const MonoTab TAB = build_tab();

__global__ __launch_bounds__(1024) void fused_kernel(
    const float4* __restrict__ in4, const float* __restrict__ w_U,
    const float* __restrict__ w_RXZX, const float* __restrict__ scale_p,
    const float* __restrict__ bias_p, float2* __restrict__ out2, int B2)
{
    __shared__ cpx   R[24][2][2];
    __shared__ float ISc[6], ISs[6];
    __shared__ cpx   L[6][16][16];
    __shared__ cpx   Pp[4][3][16][16];   // phase-3 partials (reused as PART)
    __shared__ cpx   P1[3][16][16];
    __shared__ cpx   Dm[16][16];
    __shared__ cpx   Wf[16][16];
    __shared__ cpx   Mm[16][16];
    __shared__ float cpp[4][256];        // phase-7 partials
    __shared__ float cp[256];
    __shared__ float cf[125];

    cpx (*PART)[16][16] = (cpx(*)[16][16])Pp;   // reuse Pp after phase 3b

    const int tid = threadIdx.x;
    const int idx = blockIdx.x * 1024 + tid;    // float4 unit (2 elements)
    const int q  = tid >> 8;                    // k-quarter 0..3
    const int ct = tid & 255;
    const int i = ct >> 4, j = ct & 15;
    const int k0 = q << 2;

    // ---- eval prep (all threads, before the chain) ----
    float4 f = make_float4(0.f, 0.f, 0.f, 0.f);
    if (idx < B2) f = in4[idx];
    const float scale = scale_p[0], bias = bias_p[0];
    float xp[2][5], yp[2][5], zp[2][5];
    #pragma unroll
    for (int e = 0; e < 2; ++e) {
        const float f0 = e ? f.z : f.x;
        const float f1 = e ? f.w : f.y;
        float s0, c0, s1, c1;
        sincosf(f0, &s0, &c0);
        sincosf(f1, &s1, &c1);
        const float x = s1 * c0, y = s1 * s0, z = c1;
        xp[e][0] = yp[e][0] = zp[e][0] = 1.f;
        #pragma unroll
        for (int k = 1; k < 5; ++k) {
            xp[e][k] = xp[e][k - 1] * x;
            yp[e][k] = yp[e][k - 1] * y;
            zp[e][k] = zp[e][k - 1] * z;
        }
    }

    // ---- Phase 1: 2x2 RXZX gates + iSWAP params ----
    if (tid < 24) {
        const float ta = w_RXZX[tid * 3 + 0];
        const float tb = w_RXZX[tid * 3 + 1];
        const float tc = w_RXZX[tid * 3 + 2];
        float sa, ca, sb, cb, sc, cc;
        sincosf(0.5f * ta, &sa, &ca);
        sincosf(0.5f * tb, &sb, &cb);
        sincosf(0.5f * tc, &sc, &cc);
        // RX(t)=[[c,-is],[-is,c]], RZ(t)=diag(c-is,c+is); g = RX(a)RZ(b)RX(c)
        const cpx e0 = { cb, -sb };
        const cpx e1 = { cb,  sb };
        const cpx T00 = { e0.re * cc, e0.im * cc };
        const cpx T01 = { -e0.im * (-sc), e0.re * (-sc) };
        const cpx T10 = { -e1.im * (-sc), e1.re * (-sc) };
        const cpx T11 = { e1.re * cc, e1.im * cc };
        R[tid][0][0] = { ca * T00.re + sa * T10.im, ca * T00.im - sa * T10.re };
        R[tid][0][1] = { ca * T01.re + sa * T11.im, ca * T01.im - sa * T11.re };
        R[tid][1][0] = { sa * T00.im + ca * T10.re, -sa * T00.re + ca * T10.im };
        R[tid][1][1] = { sa * T01.im + ca * T11.re, -sa * T01.re + ca * T11.im };
    } else if (tid < 30) {
        const int l = tid - 24;
        float s, c;
        sincosf(w_U[l], &s, &c);
        ISc[l] = c;
        ISs[l] = s;
    }
    __syncthreads();

    // ---- Phase 2: L[l] build; layers l = q, q+4 (1536 items / 1024 thr) ----
    for (int l = q; l < 6; l += 4) {
        const int code = (int)((0xD89C8DC98DC9ULL >> (8 * l)) & 0xFF);
        const int qa = code & 3, qb = (code >> 2) & 3;
        const int qr = (code >> 4) & 3, qs = (code >> 6) & 3;
        const int uAi = (((i >> (3 - qa)) & 1) << 1) | ((i >> (3 - qb)) & 1);
        const int uAj = (((j >> (3 - qa)) & 1) << 1) | ((j >> (3 - qb)) & 1);
        const int uBi = (((i >> (3 - qr)) & 1) << 1) | ((i >> (3 - qs)) & 1);
        const int uBj = (((j >> (3 - qr)) & 1) << 1) | ((j >> (3 - qs)) & 1);
        const int ra = l * 4 + qa, rb = l * 4 + qb;
        cpx ga;
        if (uAj == 0)      ga = cmul(R[ra][uAi >> 1][0], R[rb][uAi & 1][0]);
        else if (uAj == 3) ga = cmul(R[ra][uAi >> 1][1], R[rb][uAi & 1][1]);
        else {
            const cpx k1 = cmul(R[ra][uAi >> 1][0], R[rb][uAi & 1][1]);
            const cpx k2 = cmul(R[ra][uAi >> 1][1], R[rb][uAi & 1][0]);
            const cpx tc = (uAj == 1) ? k1 : k2;   // * cos
            const cpx ts = (uAj == 1) ? k2 : k1;   // * i sin
            const float c = ISc[l], s = ISs[l];
            ga.re = c * tc.re - s * ts.im;
            ga.im = c * tc.im + s * ts.re;
        }
        const cpx gb = cmul(R[l * 4 + qr][uBi >> 1][uBj >> 1],
                            R[l * 4 + qs][uBi & 1][uBj & 1]);
        L[l][i][j] = cmul(ga, gb);
    }
    __syncthreads();

    // ---- Phase 3: Pp[q][m] = quarter-k partial of L[2m+1]*L[2m] ----
    {
        cpx a0 = {0.f, 0.f}, a1 = {0.f, 0.f}, a2 = {0.f, 0.f};
        #pragma unroll
        for (int kk = 0; kk < 4; ++kk) {
            const int k = k0 + kk;
            a0 = cfma_(a0, L[1][i][k], L[0][k][j]);
            a1 = cfma_(a1, L[3][i][k], L[2][k][j]);
            a2 = cfma_(a2, L[5][i][k], L[4][k][j]);
        }
        Pp[q][0][i][j] = a0; Pp[q][1][i][j] = a1; Pp[q][2][i][j] = a2;
    }
    __syncthreads();

    // ---- Phase 3b: reduce 4 partials (768 items, ascending q order) ----
    if (tid < 768) {
        const int m = tid >> 8, e = tid & 255, i2 = e >> 4, j2 = e & 15;
        cpx s = Pp[0][m][i2][j2];
        #pragma unroll
        for (int u = 1; u < 4; ++u) {
            const cpx t = Pp[u][m][i2][j2];
            s.re += t.re; s.im += t.im;
        }
        P1[m][i2][j2] = s;
    }
    __syncthreads();

    // ---- Phase 4: PART[q] = quarter-k partial of P1[1]*P1[0] ----
    {
        cpx acc = {0.f, 0.f};
        #pragma unroll
        for (int kk = 0; kk < 4; ++kk) {
            const int k = k0 + kk;
            acc = cfma_(acc, P1[1][i][k], P1[0][k][j]);
        }
        PART[q][i][j] = acc;
    }
    __syncthreads();
    if (tid < 256) {
        cpx s = PART[0][i][j];
        #pragma unroll
        for (int u = 1; u < 4; ++u) {
            const cpx t = PART[u][i][j];
            s.re += t.re; s.im += t.im;
        }
        Dm[i][j] = s;
    }
    __syncthreads();

    // ---- Phase 5: W = P1[2]*D (same split) ----
    {
        cpx acc = {0.f, 0.f};
        #pragma unroll
        for (int kk = 0; kk < 4; ++kk) {
            const int k = k0 + kk;
            acc = cfma_(acc, P1[2][i][k], Dm[k][j]);
        }
        PART[q][i][j] = acc;
    }
    __syncthreads();
    if (tid < 256) {
        cpx s = PART[0][i][j];
        #pragma unroll
        for (int u = 1; u < 4; ++u) {
            const cpx t = PART[u][i][j];
            s.re += t.re; s.im += t.im;
        }
        Wf[i][j] = s;
    }
    __syncthreads();

    // ---- Phase 6: M[i][j] = sum_k zk conj(W[k][i]) W[k][j] (same split) ----
    {
        cpx acc = {0.f, 0.f};
        #pragma unroll
        for (int kk = 0; kk < 4; ++kk) {
            const int k = k0 + kk;
            const float zk = (k < 8) ? 1.f : -1.f;
            const cpx a = Wf[k][i];
            const cpx b = Wf[k][j];
            acc.re += zk * (a.re * b.re + a.im * b.im);   // conj(a)*b
            acc.im += zk * (a.re * b.im - a.im * b.re);
        }
        PART[q][i][j] = acc;
    }
    __syncthreads();
    if (tid < 256) {
        cpx s = PART[0][i][j];
        #pragma unroll
        for (int u = 1; u < 4; ++u) {
            const cpx t = PART[u][i][j];
            s.re += t.re; s.im += t.im;
        }
        Mm[i][j] = s;
    }
    __syncthreads();

    // ---- Phase 7: Pauli-trace partials over col quarter (p = ct) ----
    {
        const int p = ct;
        float accre = 0.f;
        #pragma unroll
        for (int cc = 0; cc < 4; ++cc) {
            const int col = k0 + cc;
            int row = 0;
            cpx val = {1.f, 0.f};
            #pragma unroll
            for (int k = 0; k < 4; ++k) {
                const int pk = (p >> (6 - 2 * k)) & 3;
                const int b = (col >> (3 - k)) & 1;
                int rb = b;
                if (pk == 1) {
                    rb = b ^ 1;
                } else if (pk == 2) {
                    rb = b ^ 1;
                    const cpx fc = {0.f, b ? -1.f : 1.f};
                    val = cmul(val, fc);
                } else if (pk == 3) {
                    if (b) { val.re = -val.re; val.im = -val.im; }
                }
                row |= rb << (3 - k);
            }
            const cpx mv = Mm[col][row];
            accre += mv.re * val.re - mv.im * val.im;
        }
        cpp[q][p] = accre;
    }
    __syncthreads();
    if (tid < 256) {
        float s = cpp[0][tid];
        #pragma unroll
        for (int u = 1; u < 4; ++u) s += cpp[u][tid];
        cp[tid] = s * (1.f / 16.f);
    }
    __syncthreads();

    // ---- Phase 8: collapse via compile-time table ----
    if (tid < 125) {
        const int cnt = TAB.cnt[tid];
        float s = 0.f;
        for (int k = 0; k < cnt; ++k)          // ascending: deterministic
            s += cp[TAB.idx[tid][k]];
        cf[tid] = s;
    }
    __syncthreads();

    // ---- eval finish: 2 elements per thread from LDS coefficients ----
    if (idx >= B2) return;

    float2 res;
    #pragma unroll
    for (int e = 0; e < 2; ++e) {
        float Z = 0.f;
        #pragma unroll
        for (int a = 0; a <= 4; ++a)
            #pragma unroll
            for (int b = 0; b <= 4 - a; ++b)
                #pragma unroll
                for (int c = 0; c <= 4 - a - b; ++c)
                    Z = fmaf(cf[(a * 5 + b) * 5 + c],
                             xp[e][a] * yp[e][b] * zp[e][c], Z);
        const float noise = 0.04472135954999579f * (Z * Z - 1.f) * 0.25f;
        const float v = scale * (Z + noise) + bias;
        if (e) res.y = v; else res.x = v;
    }
    out2[idx] = res;
}

extern "C" void kernel_launch(void* const* d_in, const int* in_sizes, int n_in,
                              void* d_out, int out_size, void* d_ws, size_t ws_size,
                              hipStream_t stream) {
    const float* inputs  = (const float*)d_in[0];   // [B,2] f32
    const float* w_U     = (const float*)d_in[1];   // [6]
    const float* w_RXZX  = (const float*)d_in[2];   // [6,4,3]
    const float* scale_p = (const float*)d_in[3];   // [1]
    const float* bias_p  = (const float*)d_in[4];   // [1]
    float* out = (float*)d_out;

    const int B  = in_sizes[0] / 2;                 // elements
    const int B2 = B / 2;                           // float4 units (2 el/thr)
    const int nblocks = (B2 + 1023) / 1024;

    fused_kernel<<<nblocks, 1024, 0, stream>>>(
        (const float4*)inputs, w_U, w_RXZX, scale_p, bias_p, (float2*)out, B2);
}